// Round 8
// baseline (194.652 us; speedup 1.0000x reference)
//
#include <hip/hip_runtime.h>

// SemanticCaps dynamic routing, fp32. B=128, J=10, K=1152, M=16, I=8.
// R12: barrier-free iter. Lane = (b2,m) [4 batches x 16 m], wave-internal
// softmax via width-16 shuffle reduce — the j-coupling never leaves the
// wave, so the per-k 10-wave __syncthreads convoy (R5..R11 structure) is
// gone entirely. Ws rows read coalesced (16 m-lanes = contiguous 512B,
// 4 b-groups broadcast, L1-resident slice). x staged per block with NO
// transpose (16-lane groups broadcast-read x[b,k,:]). 1536 blocks -> 6
// blocks/CU, waves fully independent.
// Falsified on the way here: Ws scalar-path stalls (R6), squash serial
// fold (R9, minor), barrier-window pipelining (R11, zero), grid-wide sync
// primitives (R3/R10: ~55 µs each), atomic reduction (R4/R8).
// b-logit algebra: b after t iters = u.(v0+..+v_{t-1}) (b starts at 0).
//
// ws (floats): sp[192*10*128*16] v0T[20480] vsumT[20480]

#define B_ 128
#define J_ 10
#define K_ 1152
#define M_ 16
#define I_ 8
#define KT 6
#define NKT (K_ / KT)        // 192 k-tiles
#define RW (K_ * I_)         // 9216 floats per x batch-row
#define SVEC (J_ * B_ * M_)  // 20480 floats per fold-slice of sp
#define XROW (KT * I_)       // 48 floats per b-row of the x tile

// ---------- routing pass -----------------------------------------------------
// MODE 0: c == 1 (iteration 0; 0.1 folded into squash<0>)
// MODE 1: c = softmax_j(u . vin);  s = sum_k c*u
// grid (NKT, 8), block 256 = 4 waves x (4 b x 16 m). Thread owns m-component
// of all 10 j's for one b; loops over KT k's. No barriers after staging.
template <int MODE>
__global__ __launch_bounds__(256, 6)
void iter_kernel(const float* __restrict__ x, const float* __restrict__ Ws,
                 const float* __restrict__ vinT, float* __restrict__ sp) {
    __shared__ float xt[16][XROW];           // 16 b-rows, no transpose, 3 KB
    const int t  = threadIdx.x;
    const int kt = blockIdx.x, by = blockIdx.y;

    // ---- stage x[by*16 .. +16)[kt*KT .. +KT)[0..8) (coalesced, layout kept)
    {
        const float4* x4 = (const float4*)x;          // row stride RW/4 = 2304
        for (int idx = t; idx < 16 * (XROW / 4); idx += 256) {
            const int bb = idx / (XROW / 4), q = idx % (XROW / 4);
            ((float4*)xt[bb])[q] =
                x4[(size_t)(by * 16 + bb) * (RW / 4) + kt * (XROW / 4) + q];
        }
    }

    const int l  = t & 63;
    const int w  = t >> 6;
    const int m  = l & 15;                   // m-lane
    const int bb = w * 4 + (l >> 4);         // local b 0..15
    const int b  = by * 16 + bb;

    float v[J_], s[J_];
#pragma unroll
    for (int j = 0; j < J_; ++j) s[j] = 0.f;
    if (MODE == 1) {
#pragma unroll
        for (int j = 0; j < J_; ++j)
            v[j] = vinT[((size_t)j * B_ + b) * M_ + m];
    }
    __syncthreads();                          // x-tile ready; last barrier

    // lane's Ws base: + j*K_*M_*I_ + kk*M_*I_ walks (j, k)
    const float* wp = Ws + ((size_t)kt * KT * M_ + m) * I_;

    for (int kk = 0; kk < KT; ++kk) {
        const float4 xa = *(const float4*)&xt[bb][kk * I_];
        const float4 xb = *(const float4*)&xt[bb][kk * I_ + 4];

        float u[J_], e[J_];
        float den = 0.f;
#pragma unroll
        for (int j = 0; j < J_; ++j) {
            const float* wr = wp + ((size_t)j * K_ + kk) * (M_ * I_);
            const float4 a4 = *(const float4*)wr;
            const float4 b4 = *(const float4*)(wr + 4);
            u[j] = a4.x * xa.x + a4.y * xa.y + a4.z * xa.z + a4.w * xa.w
                 + b4.x * xb.x + b4.y * xb.y + b4.z * xb.z + b4.w * xb.w;
            if (MODE == 1) {
                float p = u[j] * v[j];        // 16-lane tree sum over m
                p += __shfl_xor(p, 1, 16);
                p += __shfl_xor(p, 2, 16);
                p += __shfl_xor(p, 4, 16);
                p += __shfl_xor(p, 8, 16);
                e[j] = __expf(p);
                den += e[j];
            }
        }
        if (MODE == 1) {
            const float inv = __fdividef(1.f, den);
#pragma unroll
            for (int j = 0; j < J_; ++j) s[j] = fmaf(e[j] * inv, u[j], s[j]);
        } else {
#pragma unroll
            for (int j = 0; j < J_; ++j) s[j] += u[j];
        }
    }

#pragma unroll
    for (int j = 0; j < J_; ++j)
        sp[(((size_t)kt * J_ + j) * B_ + b) * M_ + m] = s[j];
}

// ---------- squash: parallel fold of 192 tile-partials, emit v ---------------
// 320 blocks x 256 thr; 4 waves each fold 48 slices for 64 outputs, LDS fold,
// wave 0 does the m-shuffle norm + emit.
// SM 0: v0T = squash(0.1*S)  SM 1: vsumT = v0T + squash(S)  SM 2: out = squash(S)
template <int SM>
__global__ __launch_bounds__(256)
void squash_kernel(const float* __restrict__ sp, const float* __restrict__ v0T,
                   float* __restrict__ dst) {
    __shared__ float red[4][64];
    const int t  = threadIdx.x;
    const int l  = t & 63;
    const int wv = t >> 6;
    const int g  = blockIdx.x * 64 + l;   // g = (j*128+b)*16+m
    const int m = g & 15;
    const int b = (g >> 4) & 127;
    const int j = g >> 11;
    const float* p = sp + (size_t)((j * B_ + b) * M_ + m);
    float S = 0.f;
#pragma unroll 8
    for (int tt = wv * (NKT / 4); tt < (wv + 1) * (NKT / 4); ++tt)
        S += p[(size_t)tt * SVEC];
    red[wv][l] = S;
    __syncthreads();
    if (wv == 0) {
        S = red[0][l] + red[1][l] + red[2][l] + red[3][l];
        if (SM == 0) S *= 0.1f;
        float sq = S * S;
        sq += __shfl_xor(sq, 1, 64);
        sq += __shfl_xor(sq, 2, 64);
        sq += __shfl_xor(sq, 4, 64);
        sq += __shfl_xor(sq, 8, 64);      // sum over m within 16-lane group
        const float n = sqrtf(sq);
        float v = S * (n / (1.f + sq));
        if (SM == 1) v += v0T[g];
        if (SM == 2) dst[((size_t)b * J_ + j) * M_ + m] = v;   // standard [b][j][m]
        else         dst[g] = v;                                // vT layout
    }
}

extern "C" void kernel_launch(void* const* d_in, const int* in_sizes, int n_in,
                              void* d_out, int out_size, void* d_ws, size_t ws_size,
                              hipStream_t stream) {
    const float* x  = (const float*)d_in[0];   // [128][1152][8]
    const float* Ws = (const float*)d_in[1];   // [10][1152][16][8]
    float* out = (float*)d_out;                // [128][10][16]

    float* sp    = (float*)d_ws;                           // 3,932,160 floats
    float* v0T   = sp + (size_t)NKT * SVEC;                //    20,480
    float* vsumT = v0T + SVEC;                             //    20,480

    iter_kernel<0><<<dim3(NKT, 8), 256, 0, stream>>>(x, Ws, nullptr, sp);
    squash_kernel<0><<<320, 256, 0, stream>>>(sp, nullptr, v0T);

    iter_kernel<1><<<dim3(NKT, 8), 256, 0, stream>>>(x, Ws, v0T, sp);
    squash_kernel<1><<<320, 256, 0, stream>>>(sp, v0T, vsumT);

    iter_kernel<1><<<dim3(NKT, 8), 256, 0, stream>>>(x, Ws, vsumT, sp);
    squash_kernel<2><<<320, 256, 0, stream>>>(sp, nullptr, out);
}

// Round 9
// 158.649 us; speedup vs baseline: 1.2269x; 1.2269x over previous
//
#include <hip/hip_runtime.h>

// SemanticCaps dynamic routing, fp32. B=128, J=10, K=1152, M=16, I=8.
// R13 = R12 with ONE change: the __launch_bounds__(256, 6) min-occupancy
// bound removed. R12's counters showed VGPR_Count=40 + WRITE_SIZE 67.9 MB
// vs 15.7 algorithmic -> the forced 6-waves/EU cap spilled the ~40-float
// per-thread state (u/e/s/v arrays) to scratch; 52 MB/pass of scratch
// round-trip at 26% VALUBusy was the whole 53.6 µs. Structure unchanged:
// barrier-free iter, lane=(b2,m), wave-internal width-16 shuffle softmax,
// coalesced Ws rows, no x transpose, 1536 independent blocks.
// Falsified so far: Ws scalar-path stalls (R6), squash serial fold (R9),
// barrier-window pipelining (R11), grid-sync primitives (R3/R10 ~55 µs),
// atomic reduction (R4/R8 fabric serialization), forced occupancy (R12).
// b-logit algebra: b after t iters = u.(v0+..+v_{t-1}) (b starts at 0).
//
// ws (floats): sp[192*10*128*16] v0T[20480] vsumT[20480]

#define B_ 128
#define J_ 10
#define K_ 1152
#define M_ 16
#define I_ 8
#define KT 6
#define NKT (K_ / KT)        // 192 k-tiles
#define RW (K_ * I_)         // 9216 floats per x batch-row
#define SVEC (J_ * B_ * M_)  // 20480 floats per fold-slice of sp
#define XROW (KT * I_)       // 48 floats per b-row of the x tile

// ---------- routing pass -----------------------------------------------------
// MODE 0: c == 1 (iteration 0; 0.1 folded into squash<0>)
// MODE 1: c = softmax_j(u . vin);  s = sum_k c*u
// grid (NKT, 8), block 256 = 4 waves x (4 b x 16 m). Thread owns m-component
// of all 10 j's for one b; loops over KT k's. No barriers after staging.
template <int MODE>
__global__ __launch_bounds__(256)
void iter_kernel(const float* __restrict__ x, const float* __restrict__ Ws,
                 const float* __restrict__ vinT, float* __restrict__ sp) {
    __shared__ float xt[16][XROW];           // 16 b-rows, no transpose, 3 KB
    const int t  = threadIdx.x;
    const int kt = blockIdx.x, by = blockIdx.y;

    // ---- stage x[by*16 .. +16)[kt*KT .. +KT)[0..8) (coalesced, layout kept)
    {
        const float4* x4 = (const float4*)x;          // row stride RW/4 = 2304
        for (int idx = t; idx < 16 * (XROW / 4); idx += 256) {
            const int bb = idx / (XROW / 4), q = idx % (XROW / 4);
            ((float4*)xt[bb])[q] =
                x4[(size_t)(by * 16 + bb) * (RW / 4) + kt * (XROW / 4) + q];
        }
    }

    const int l  = t & 63;
    const int w  = t >> 6;
    const int m  = l & 15;                   // m-lane
    const int bb = w * 4 + (l >> 4);         // local b 0..15
    const int b  = by * 16 + bb;

    float v[J_], s[J_];
#pragma unroll
    for (int j = 0; j < J_; ++j) s[j] = 0.f;
    if (MODE == 1) {
#pragma unroll
        for (int j = 0; j < J_; ++j)
            v[j] = vinT[((size_t)j * B_ + b) * M_ + m];
    }
    __syncthreads();                          // x-tile ready; last barrier

    // lane's Ws base: + j*K_*M_*I_ + kk*M_*I_ walks (j, k)
    const float* wp = Ws + ((size_t)kt * KT * M_ + m) * I_;

    for (int kk = 0; kk < KT; ++kk) {
        const float4 xa = *(const float4*)&xt[bb][kk * I_];
        const float4 xb = *(const float4*)&xt[bb][kk * I_ + 4];

        float u[J_], e[J_];
        float den = 0.f;
#pragma unroll
        for (int j = 0; j < J_; ++j) {
            const float* wr = wp + ((size_t)j * K_ + kk) * (M_ * I_);
            const float4 a4 = *(const float4*)wr;
            const float4 b4 = *(const float4*)(wr + 4);
            u[j] = a4.x * xa.x + a4.y * xa.y + a4.z * xa.z + a4.w * xa.w
                 + b4.x * xb.x + b4.y * xb.y + b4.z * xb.z + b4.w * xb.w;
            if (MODE == 1) {
                float p = u[j] * v[j];        // 16-lane tree sum over m
                p += __shfl_xor(p, 1, 16);
                p += __shfl_xor(p, 2, 16);
                p += __shfl_xor(p, 4, 16);
                p += __shfl_xor(p, 8, 16);
                e[j] = __expf(p);
                den += e[j];
            }
        }
        if (MODE == 1) {
            const float inv = __fdividef(1.f, den);
#pragma unroll
            for (int j = 0; j < J_; ++j) s[j] = fmaf(e[j] * inv, u[j], s[j]);
        } else {
#pragma unroll
            for (int j = 0; j < J_; ++j) s[j] += u[j];
        }
    }

#pragma unroll
    for (int j = 0; j < J_; ++j)
        sp[(((size_t)kt * J_ + j) * B_ + b) * M_ + m] = s[j];
}

// ---------- squash: parallel fold of 192 tile-partials, emit v ---------------
// 320 blocks x 256 thr; 4 waves each fold 48 slices for 64 outputs, LDS fold,
// wave 0 does the m-shuffle norm + emit.
// SM 0: v0T = squash(0.1*S)  SM 1: vsumT = v0T + squash(S)  SM 2: out = squash(S)
template <int SM>
__global__ __launch_bounds__(256)
void squash_kernel(const float* __restrict__ sp, const float* __restrict__ v0T,
                   float* __restrict__ dst) {
    __shared__ float red[4][64];
    const int t  = threadIdx.x;
    const int l  = t & 63;
    const int wv = t >> 6;
    const int g  = blockIdx.x * 64 + l;   // g = (j*128+b)*16+m
    const int m = g & 15;
    const int b = (g >> 4) & 127;
    const int j = g >> 11;
    const float* p = sp + (size_t)((j * B_ + b) * M_ + m);
    float S = 0.f;
#pragma unroll 8
    for (int tt = wv * (NKT / 4); tt < (wv + 1) * (NKT / 4); ++tt)
        S += p[(size_t)tt * SVEC];
    red[wv][l] = S;
    __syncthreads();
    if (wv == 0) {
        S = red[0][l] + red[1][l] + red[2][l] + red[3][l];
        if (SM == 0) S *= 0.1f;
        float sq = S * S;
        sq += __shfl_xor(sq, 1, 64);
        sq += __shfl_xor(sq, 2, 64);
        sq += __shfl_xor(sq, 4, 64);
        sq += __shfl_xor(sq, 8, 64);      // sum over m within 16-lane group
        const float n = sqrtf(sq);
        float v = S * (n / (1.f + sq));
        if (SM == 1) v += v0T[g];
        if (SM == 2) dst[((size_t)b * J_ + j) * M_ + m] = v;   // standard [b][j][m]
        else         dst[g] = v;                                // vT layout
    }
}

extern "C" void kernel_launch(void* const* d_in, const int* in_sizes, int n_in,
                              void* d_out, int out_size, void* d_ws, size_t ws_size,
                              hipStream_t stream) {
    const float* x  = (const float*)d_in[0];   // [128][1152][8]
    const float* Ws = (const float*)d_in[1];   // [10][1152][16][8]
    float* out = (float*)d_out;                // [128][10][16]

    float* sp    = (float*)d_ws;                           // 3,932,160 floats
    float* v0T   = sp + (size_t)NKT * SVEC;                //    20,480
    float* vsumT = v0T + SVEC;                             //    20,480

    iter_kernel<0><<<dim3(NKT, 8), 256, 0, stream>>>(x, Ws, nullptr, sp);
    squash_kernel<0><<<320, 256, 0, stream>>>(sp, nullptr, v0T);

    iter_kernel<1><<<dim3(NKT, 8), 256, 0, stream>>>(x, Ws, v0T, sp);
    squash_kernel<1><<<320, 256, 0, stream>>>(sp, v0T, vsumT);

    iter_kernel<1><<<dim3(NKT, 8), 256, 0, stream>>>(x, Ws, vsumT, sp);
    squash_kernel<2><<<320, 256, 0, stream>>>(sp, nullptr, out);
}